// Round 17
// baseline (100.085 us; speedup 1.0000x reference)
//
#include <hip/hip_runtime.h>
#include <math.h>
#include <stdint.h>

// B=16, R=Hr*Wr=4096, Q=Hq*Wq=1024.
// conf_ref*conf_qry = exp((ar+aq)*x) / (CS_q * RS_r),
//   CS_q = sum_r exp(ar*x), RS_r = sum_q exp(aq*x)  (max-shifts cancel exactly).
// out[r] = exp(0.5*(max_q[(ar+aq)*x - ln CS_q] - ln RS_r))
//
// r16 post-mortem: all VGPR-staged row-stat streamers run ~5000 cyc/KB/wave
// = one latency round-trip per row-iter (loads can't hoist past the branchy
// consumer). Fix = the untried CDNA4 idiom: __builtin_amdgcn_global_load_lds
// staging (no dest VGPRs, fire-and-forget, 16KB/block in flight), 4-row
// double-buffered windows, one __syncthreads per window (its vmcnt(0) drain
// is the staging fence). Processing body identical to r11/r16.
// Soundness exact: best >= s2*th - cmin, else 4KB row re-read fallback.

constexpr int B = 16;
constexpr int R = 4096;
constexpr int Q = 1024;
constexpr int CAP = 32;
constexpr int CHROWS = 16;             // rows per block
constexpr int NCH = R / CHROWS;        // 256 chunks per batch
constexpr int NBLK = B * NCH;          // 4096 blocks
#define DTH 1.0f                       // th = mean(8 sampled row maxes) - DTH
#define ECLAMP 80.f                    // exp arg clamp (keeps fp32 finite)

__device__ __forceinline__ float wmax64(float v) {
#pragma unroll
    for (int o = 32; o; o >>= 1) v = fmaxf(v, __shfl_xor(v, o, 64));
    return v;
}
__device__ __forceinline__ float max4(float4 v) {
    return fmaxf(fmaxf(v.x, v.y), fmaxf(v.z, v.w));
}
// order-preserving float<->uint for atomicMin on floats
__device__ __forceinline__ uint32_t encf(float f) {
    uint32_t u = __float_as_uint(f);
    return (u & 0x80000000u) ? ~u : (u | 0x80000000u);
}
__device__ __forceinline__ float decf(uint32_t e) {
    uint32_t u = (e & 0x80000000u) ? (e & 0x7FFFFFFFu) : ~e;
    return __uint_as_float(u);
}
// th from the 8 sampled row maxes (same FP order everywhere -> same value)
__device__ __forceinline__ float th_of(const float* rmSamp, int b) {
    float s = 0.f;
#pragma unroll
    for (int i = 0; i < 8; ++i) s += rmSamp[b * 8 + i];
    return s * 0.125f - DTH;
}

// ---------------- Sampler: rmSamp[b*8+k] = max of row k*512 ----------------
__global__ __launch_bounds__(256) void qatm_sample(const float* __restrict__ x,
                                                   float* __restrict__ rmSamp,
                                                   uint32_t* __restrict__ cminEnc) {
    const int blk = blockIdx.x;
    const int b = blk >> 3, k = blk & 7;
    const int t = threadIdx.x;
    if (k == 0 && t == 0) cminEnc[b] = 0xFFFFFFFFu;
    const float4* xr = reinterpret_cast<const float4*>(x) +
                       ((size_t)b * R + (size_t)k * 512) * (Q / 4);
    float m = wmax64(max4(xr[t]));
    __shared__ float sh[4];
    if ((t & 63) == 0) sh[t >> 6] = m;
    __syncthreads();
    if (t == 0)
        rmSamp[blk] = fmaxf(fmaxf(sh[0], sh[1]), fmaxf(sh[2], sh[3]));
}

// ---------------- Pass 1: gload_lds-staged stream of x ----------------
// Block (b,ch) covers rows [ch*16,+16) = 64KB contiguous. 4-row (16KB)
// windows, double-buffered; wave w stages KB-slices w*4..w*4+3 of each
// window. Thread t owns float4-group t of every row (col-sums in 4 regs).
__global__ __launch_bounds__(256, 3) void qatm_pass1(
    const float* __restrict__ x,
    float* __restrict__ psum,        // [NBLK][1024] chunk col-sums of exp(ar*x)
    float2* __restrict__ rscnt,      // [B*R] (row sum, count bits)
    float4* __restrict__ cand4,      // [B*R][CAP] candidate float4s
    uint32_t* __restrict__ candg,    // [B*R][CAP] group index (= owning thread)
    const float* __restrict__ rmSamp,
    const float* __restrict__ coef_ref,
    const float* __restrict__ coef_qry)
{
    const int blk = blockIdx.x;
    const int b = blk >> 8, ch = blk & (NCH - 1);
    const int t = threadIdx.x;
    const int w = t >> 6, l = t & 63;
    const float ar = coef_ref[0], aq = coef_qry[0];
    const bool same = (ar == aq);          // uniform branch
    const float th = th_of(rmSamp, b);     // uniform scalar, hides under stream

    __shared__ float buf[2][4096];         // 2 x 16KB staging (4 rows each)
    __shared__ float ssum[CHROWS][257];    // +1 pad
    __shared__ int cnt_sh[CHROWS];

    const size_t row0 = (size_t)b * R + (size_t)ch * CHROWS;
    const float* xbase = x + row0 * Q;     // block's 64KB, contiguous

    if (t < CHROWS) cnt_sh[t] = 0;

    // stage window win into buf[pb]: 16 gloads (4 per wave), linear dest
#define STAGE(win, pb)                                                         \
    {                                                                          \
        const float* s0 = xbase + (size_t)(win) * 4096 + (w * 4) * 256 + l * 4;\
        float* d0 = &buf[pb][(w * 4) * 256];                                   \
        _Pragma("unroll")                                                      \
        for (int j = 0; j < 4; ++j)                                            \
            __builtin_amdgcn_global_load_lds(                                  \
                (const __attribute__((address_space(1))) void*)(s0 + j * 256), \
                (__attribute__((address_space(3))) void*)(d0 + j * 256),       \
                16, 0, 0);                                                     \
    }

    STAGE(0, 0);
    float4 c = {0.f, 0.f, 0.f, 0.f};       // col-sum accumulator
    int cur = 0;

    for (int win = 0; win < 4; ++win) {
        __syncthreads();                   // vmcnt(0) drain: buf[cur] ready,
                                           // prev window's reads complete
        if (win < 3) STAGE(win + 1, cur ^ 1);
#pragma unroll
        for (int rr = 0; rr < 4; ++rr) {
            const int r = win * 4 + rr;
            float4 v = reinterpret_cast<const float4*>(&buf[cur][rr * 1024])[t];
            float4 e;
            e.x = __expf(fminf(ar * v.x, ECLAMP));
            e.y = __expf(fminf(ar * v.y, ECLAMP));
            e.z = __expf(fminf(ar * v.z, ECLAMP));
            e.w = __expf(fminf(ar * v.w, ECLAMP));
            c.x += e.x; c.y += e.y; c.z += e.z; c.w += e.w;
            float rp;
            if (same) rp = (e.x + e.y) + (e.z + e.w);
            else rp = (__expf(fminf(aq * v.x, ECLAMP)) + __expf(fminf(aq * v.y, ECLAMP))) +
                      (__expf(fminf(aq * v.z, ECLAMP)) + __expf(fminf(aq * v.w, ECLAMP)));
            ssum[r][t] = rp;               // plain ds_write, conflict-free
            if (max4(v) >= th) {           // ~10 of 256 threads per row
                int idx = atomicAdd(&cnt_sh[r], 1);
                if (idx < CAP) {
                    cand4[(row0 + r) * CAP + idx] = v;
                    candg[(row0 + r) * CAP + idx] = (uint32_t)t;
                }
            }
        }
        cur ^= 1;
    }
#undef STAGE

    __syncthreads();
    {   // row reduce: 16 threads per row; thread (row=t>>4, seg=t&15) sums
        // every-16th slot (addr = row*257 + seg + 16i -> ~2-way banks, free)
        const int row = t >> 4, seg = t & 15;
        float p = 0.f;
#pragma unroll
        for (int i = 0; i < 16; ++i) p += ssum[row][seg + 16 * i];
        p += __shfl_xor(p, 1, 64);
        p += __shfl_xor(p, 2, 64);
        p += __shfl_xor(p, 4, 64);
        p += __shfl_xor(p, 8, 64);
        if (seg == 0)
            rscnt[row0 + row] = make_float2(p, __uint_as_float((uint32_t)cnt_sh[row]));
    }
    reinterpret_cast<float4*>(psum)[(size_t)blk * 256 + t] = c;   // coalesced
}

// ---------------- Combine: cvec = ln CS; cmin via atomicMin ----------------
__global__ __launch_bounds__(256) void qatm_combine(
    const float* __restrict__ psum, float* __restrict__ cvec,
    uint32_t* __restrict__ cminEnc)
{
    const int b = blockIdx.x >> 4, part = blockIdx.x & 15;
    const int t = threadIdx.x;
    const int col = part * 64 + (t & 63);
    const int stripe = t >> 6;
    __shared__ float acc[4][64];
    float s = 0.f;
    const float* p = psum + ((size_t)b * NCH + (size_t)stripe * 64) * 1024 + col;
#pragma unroll 8
    for (int i = 0; i < 64; ++i) s += p[(size_t)i * 1024];
    acc[stripe][t & 63] = s;
    __syncthreads();
    if (t < 64) {
        float tot = (acc[0][t] + acc[1][t]) + (acc[2][t] + acc[3][t]);
        float c = __logf(tot);
        cvec[b * 1024 + col] = c;
        float m = -wmax64(-c);
        if (t == 0) atomicMin(&cminEnc[b], encf(m));
    }
}

// ---------------- Select: candidates + exact soundness check ----------------
__global__ __launch_bounds__(256) void qatm_select(
    const float* __restrict__ x, const float* __restrict__ cvec,
    const uint32_t* __restrict__ cminEnc, const float* __restrict__ rmSamp,
    const float2* __restrict__ rscnt,
    const float4* __restrict__ cand4, const uint32_t* __restrict__ candg,
    const float* __restrict__ coef_ref, const float* __restrict__ coef_qry,
    float* __restrict__ out)
{
    const int w = threadIdx.x >> 6, l = threadIdx.x & 63;
    const size_t row = (size_t)blockIdx.x * 4 + w;
    const int b = (int)(row >> 12);
    const float ar = coef_ref[0], aq = coef_qry[0], s2 = ar + aq;
    const float2 rc = rscnt[row];
    const float rs = rc.x;
    const uint32_t cnt = __float_as_uint(rc.y);

    float best = -INFINITY;
    bool fb = (cnt > CAP) || (cnt == 0) || !(s2 > 0.f);
    if (!fb) {
        if (l < (int)cnt) {
            float4 v = cand4[row * CAP + l];
            uint32_t g = candg[row * CAP + l];
            float4 c = reinterpret_cast<const float4*>(cvec)[((size_t)b << 8) + (int)(g & 255u)];
            best = fmaxf(fmaxf(s2 * v.x - c.x, s2 * v.y - c.y),
                         fmaxf(s2 * v.z - c.z, s2 * v.w - c.w));
        }
        best = wmax64(best);
        // non-candidate groups have all x < th -> score < s2*th - cmin
        if (!(best >= s2 * th_of(rmSamp, b) - decf(cminEnc[b]))) fb = true;
    }
    if (fb) {
        const float4* xr = reinterpret_cast<const float4*>(x) + row * (Q / 4);
        const float4* cq = reinterpret_cast<const float4*>(cvec) + ((size_t)b << 8);
        best = -INFINITY;
#pragma unroll
        for (int it = 0; it < 4; ++it) {
            float4 v = xr[it * 64 + l], c = cq[it * 64 + l];
            best = fmaxf(best, fmaxf(fmaxf(s2 * v.x - c.x, s2 * v.y - c.y),
                                     fmaxf(s2 * v.z - c.z, s2 * v.w - c.w)));
        }
        best = wmax64(best);
    }
    if (l == 0) out[row] = __expf(0.5f * (best - __logf(rs)));
}

extern "C" void kernel_launch(void* const* d_in, const int* in_sizes, int n_in,
                              void* d_out, int out_size, void* d_ws, size_t ws_size,
                              hipStream_t stream) {
    const float* x = (const float*)d_in[0];
    const float* coef_ref = (const float*)d_in[1];
    const float* coef_qry = (const float*)d_in[2];
    float* out = (float*)d_out;

    char* ws = (char*)d_ws;
    // layout (bytes), 16B-aligned:
    //   cand4  : B*R*CAP*16  = 32 MiB
    //   candg  : B*R*CAP*4   = 8 MiB
    //   psum   : NBLK*1024*4 = 16 MiB
    //   cvec   : B*Q*4 = 64 KiB
    //   rscnt  : B*R*8 = 512 KiB
    //   rmSamp : 512 B ; cminEnc : 64 B                  (total ~57 MiB)
    size_t off = 0;
    float4*   cand4 = (float4*)(ws + off);   off += (size_t)B * R * CAP * 16;
    uint32_t* candg = (uint32_t*)(ws + off); off += (size_t)B * R * CAP * 4;
    float*    psum  = (float*)(ws + off);    off += (size_t)NBLK * 1024 * 4;
    float*    cvec  = (float*)(ws + off);    off += (size_t)B * Q * 4;
    float2*   rscnt = (float2*)(ws + off);   off += (size_t)B * R * 8;
    float*    rmSamp= (float*)(ws + off);    off += 512;
    uint32_t* cminE = (uint32_t*)(ws + off); off += 64;

    qatm_sample<<<B * 8, 256, 0, stream>>>(x, rmSamp, cminE);
    qatm_pass1<<<NBLK, 256, 0, stream>>>(x, psum, rscnt, cand4, candg,
                                         rmSamp, coef_ref, coef_qry);
    qatm_combine<<<256, 256, 0, stream>>>(psum, cvec, cminE);
    qatm_select<<<(B * R) / 4, 256, 0, stream>>>(x, cvec, cminE, rmSamp, rscnt,
                                                 cand4, candg, coef_ref, coef_qry, out);
}

// Round 18
// 84.512 us; speedup vs baseline: 1.1843x; 1.1843x over previous
//
#include <hip/hip_runtime.h>
#include <math.h>
#include <stdint.h>

// B=16, R=Hr*Wr=4096, Q=Hq*Wq=1024.
// conf_ref*conf_qry = exp((ar+aq)*x) / (CS_q * RS_r),
//   CS_q = sum_r exp(ar*x), RS_r = sum_q exp(aq*x)  (max-shifts cancel exactly).
// out[r] = exp(0.5*(max_q[(ar+aq)*x - ln CS_q] - ln RS_r))
//
// CHAMPION (r11, 85.0us) resubmitted verbatim for reproducibility lock-in.
// 17-round ledger: the ~4.1 TB/s pace of every row-stat streaming pass1
// survived ten mechanism swaps (shuffles, windowed barriers, LDS atomics,
// deferred reduction, rare-branch append, branchless cndmask, LDS-staged
// candidates, external sampler, global_load_lds async staging) -- the
// plateau is mechanism-independent. Structural floor ~75us (268MB read +
// 32MB partials + select + combine + gaps); this kernel is ~13% above.
// Soundness exact in select: best >= s2*th - cmin, else 4KB row re-read.

constexpr int B = 16;
constexpr int R = 4096;
constexpr int Q = 1024;
constexpr int CAP = 32;
constexpr int CHROWS = 16;             // rows per block
constexpr int NCH = R / CHROWS;        // 256 chunks per batch
constexpr int NBLK = B * NCH;          // 4096 blocks
#define DTH 1.1f                       // th = chunk-sample row max - DTH

__device__ __forceinline__ float wmax64(float v) {
#pragma unroll
    for (int o = 32; o; o >>= 1) v = fmaxf(v, __shfl_xor(v, o, 64));
    return v;
}
__device__ __forceinline__ float max4(float4 v) {
    return fmaxf(fmaxf(v.x, v.y), fmaxf(v.z, v.w));
}
// order-preserving float<->uint for atomicMin on floats
__device__ __forceinline__ uint32_t encf(float f) {
    uint32_t u = __float_as_uint(f);
    return (u & 0x80000000u) ? ~u : (u | 0x80000000u);
}
__device__ __forceinline__ float decf(uint32_t e) {
    uint32_t u = (e & 0x80000000u) ? (e & 0x7FFFFFFFu) : ~e;
    return __uint_as_float(u);
}

// ---------------- Pass 1: single full stream of x ----------------
// Block (b,ch) covers rows [ch*16,+16); thread t owns float4-group t of each.
__global__ __launch_bounds__(256, 8) void qatm_pass1(
    const float* __restrict__ x,
    float* __restrict__ psum,        // [NBLK][1024] chunk col-sums of exp(ar*x)
    float2* __restrict__ rscnt,      // [B*R] (row sum, count bits)
    float4* __restrict__ cand4,      // [B*R][CAP] candidate float4s
    uint32_t* __restrict__ candg,    // [B*R][CAP] group index (= owning thread)
    float* __restrict__ thChunk,     // [NBLK]
    uint32_t* __restrict__ cminEnc,  // [B]
    const float* __restrict__ coef_ref,
    const float* __restrict__ coef_qry)
{
    const int blk = blockIdx.x;
    const int b = blk >> 8, ch = blk & (NCH - 1);
    const int t = threadIdx.x;
    const float ar = coef_ref[0], aq = coef_qry[0];
    const bool same = (ar == aq);          // uniform branch

    __shared__ float ssum[CHROWS][257];    // +1 pad: write bank = t%32, free
    __shared__ int cnt_sh[CHROWS];
    __shared__ float redsh[4];
    __shared__ float th_sh;

    if (blk < B && t == 0) cminEnc[blk] = 0xFFFFFFFFu;

    const size_t row0 = (size_t)b * R + (size_t)ch * CHROWS;
    const float4* xb = reinterpret_cast<const float4*>(x) + row0 * 256 + t;

    if (t < CHROWS) cnt_sh[t] = 0;
    {   // sample chunk's first row -> threshold (2 barriers, once per block)
        float m = wmax64(max4(xb[0]));
        if ((t & 63) == 0) redsh[t >> 6] = m;
        __syncthreads();
        if (t == 0) {
            float mm = fmaxf(fmaxf(redsh[0], redsh[1]), fmaxf(redsh[2], redsh[3]));
            th_sh = mm - DTH;
            thChunk[blk] = mm - DTH;
        }
        __syncthreads();
    }
    const float th = th_sh;

    float4 c = {0.f, 0.f, 0.f, 0.f};       // the ONLY persistent accumulator

    // ---- hot loop: 1 load, 4 exp, ~10 adds, 1 ds_write, 1 rare branch ----
#pragma unroll 4
    for (int r = 0; r < CHROWS; ++r) {
        float4 v = xb[(size_t)r * 256];
        float4 e;
        e.x = __expf(ar * v.x);
        e.y = __expf(ar * v.y);
        e.z = __expf(ar * v.z);
        e.w = __expf(ar * v.w);
        c.x += e.x; c.y += e.y; c.z += e.z; c.w += e.w;
        float rp;
        if (same) rp = (e.x + e.y) + (e.z + e.w);
        else rp = (__expf(aq * v.x) + __expf(aq * v.y)) +
                  (__expf(aq * v.z) + __expf(aq * v.w));
        ssum[r][t] = rp;                   // plain ds_write, conflict-free
        if (max4(v) >= th) {               // ~18 of 256 threads per row
            int idx = atomicAdd(&cnt_sh[r], 1);
            if (idx < CAP) {
                cand4[(row0 + r) * CAP + idx] = v;
                candg[(row0 + r) * CAP + idx] = (uint32_t)t;
            }
        }
    }

    __syncthreads();                       // the ONLY post-stream barrier
    {   // row reduce: 16 threads per row; thread (row=t>>4, seg=t&15) sums
        // every-16th slot (addr = row*257 + seg + 16i -> ~2-way banks, free)
        const int row = t >> 4, seg = t & 15;
        float p = 0.f;
#pragma unroll
        for (int i = 0; i < 16; ++i) p += ssum[row][seg + 16 * i];
        p += __shfl_xor(p, 1, 64);
        p += __shfl_xor(p, 2, 64);
        p += __shfl_xor(p, 4, 64);
        p += __shfl_xor(p, 8, 64);
        if (seg == 0)
            rscnt[row0 + row] = make_float2(p, __uint_as_float((uint32_t)cnt_sh[row]));
    }
    reinterpret_cast<float4*>(psum)[(size_t)blk * 256 + t] = c;   // coalesced
}

// ---------------- Combine: cvec = ln CS; cmin via atomicMin ----------------
// grid 256: block j -> batch j>>4, cols (j&15)*64 + (t&63); stripe t>>6
// covers 64 of the 256 chunks.
__global__ __launch_bounds__(256) void qatm_combine(
    const float* __restrict__ psum, float* __restrict__ cvec,
    uint32_t* __restrict__ cminEnc)
{
    const int b = blockIdx.x >> 4, part = blockIdx.x & 15;
    const int t = threadIdx.x;
    const int col = part * 64 + (t & 63);
    const int stripe = t >> 6;
    __shared__ float acc[4][64];
    float s = 0.f;
    const float* p = psum + ((size_t)b * NCH + (size_t)stripe * 64) * 1024 + col;
#pragma unroll 8
    for (int i = 0; i < 64; ++i) s += p[(size_t)i * 1024];
    acc[stripe][t & 63] = s;
    __syncthreads();
    if (t < 64) {
        float tot = (acc[0][t] + acc[1][t]) + (acc[2][t] + acc[3][t]);
        float c = __logf(tot);
        cvec[b * 1024 + col] = c;
        float m = -wmax64(-c);
        if (t == 0) atomicMin(&cminEnc[b], encf(m));
    }
}

// ---------------- Select: candidates + exact soundness check ----------------
__global__ __launch_bounds__(256) void qatm_select(
    const float* __restrict__ x, const float* __restrict__ cvec,
    const uint32_t* __restrict__ cminEnc, const float* __restrict__ thChunk,
    const float2* __restrict__ rscnt,
    const float4* __restrict__ cand4, const uint32_t* __restrict__ candg,
    const float* __restrict__ coef_ref, const float* __restrict__ coef_qry,
    float* __restrict__ out)
{
    const int w = threadIdx.x >> 6, l = threadIdx.x & 63;
    const size_t row = (size_t)blockIdx.x * 4 + w;
    const int b = (int)(row >> 12);
    const float ar = coef_ref[0], aq = coef_qry[0], s2 = ar + aq;
    const float2 rc = rscnt[row];
    const float rs = rc.x;
    const uint32_t cnt = __float_as_uint(rc.y);

    float best = -INFINITY;
    bool fb = (cnt > CAP) || (cnt == 0) || !(s2 > 0.f);
    if (!fb) {
        if (l < (int)cnt) {
            float4 v = cand4[row * CAP + l];
            uint32_t g = candg[row * CAP + l];
            float4 c = reinterpret_cast<const float4*>(cvec)[((size_t)b << 8) + (int)(g & 255u)];
            best = fmaxf(fmaxf(s2 * v.x - c.x, s2 * v.y - c.y),
                         fmaxf(s2 * v.z - c.z, s2 * v.w - c.w));
        }
        best = wmax64(best);
        // non-candidate groups have all x < th -> score < s2*th - cmin
        if (!(best >= s2 * thChunk[row >> 4] - decf(cminEnc[b]))) fb = true;
    }
    if (fb) {
        const float4* xr = reinterpret_cast<const float4*>(x) + row * (Q / 4);
        const float4* cq = reinterpret_cast<const float4*>(cvec) + ((size_t)b << 8);
        best = -INFINITY;
#pragma unroll
        for (int it = 0; it < 4; ++it) {
            float4 v = xr[it * 64 + l], c = cq[it * 64 + l];
            best = fmaxf(best, fmaxf(fmaxf(s2 * v.x - c.x, s2 * v.y - c.y),
                                     fmaxf(s2 * v.z - c.z, s2 * v.w - c.w)));
        }
        best = wmax64(best);
    }
    if (l == 0) out[row] = __expf(0.5f * (best - __logf(rs)));
}

extern "C" void kernel_launch(void* const* d_in, const int* in_sizes, int n_in,
                              void* d_out, int out_size, void* d_ws, size_t ws_size,
                              hipStream_t stream) {
    const float* x = (const float*)d_in[0];
    const float* coef_ref = (const float*)d_in[1];
    const float* coef_qry = (const float*)d_in[2];
    float* out = (float*)d_out;

    char* ws = (char*)d_ws;
    // layout (bytes), 16B-aligned:
    //   cand4  : B*R*CAP*16  = 32 MiB
    //   candg  : B*R*CAP*4   = 8 MiB
    //   psum   : NBLK*1024*4 = 16 MiB
    //   cvec   : B*Q*4 = 64 KiB
    //   rscnt  : B*R*8 = 512 KiB
    //   thChunk: NBLK*4 = 16 KiB ; cminEnc : 64 B       (total ~57 MiB)
    size_t off = 0;
    float4*   cand4 = (float4*)(ws + off);   off += (size_t)B * R * CAP * 16;
    uint32_t* candg = (uint32_t*)(ws + off); off += (size_t)B * R * CAP * 4;
    float*    psum  = (float*)(ws + off);    off += (size_t)NBLK * 1024 * 4;
    float*    cvec  = (float*)(ws + off);    off += (size_t)B * Q * 4;
    float2*   rscnt = (float2*)(ws + off);   off += (size_t)B * R * 8;
    float*    thA   = (float*)(ws + off);    off += (size_t)NBLK * 4;
    uint32_t* cminE = (uint32_t*)(ws + off); off += 64;

    qatm_pass1<<<NBLK, 256, 0, stream>>>(x, psum, rscnt, cand4, candg,
                                         thA, cminE, coef_ref, coef_qry);
    qatm_combine<<<256, 256, 0, stream>>>(psum, cvec, cminE);
    qatm_select<<<(B * R) / 4, 256, 0, stream>>>(x, cvec, cminE, thA, rscnt,
                                                 cand4, candg, coef_ref, coef_qry, out);
}